// Round 1
// baseline (4607.738 us; speedup 1.0000x reference)
//
#include <hip/hip_runtime.h>
#include <hip/hip_bf16.h>
#include <math.h>
#include <stdint.h>

// Problem constants (B=4, T=4096, D=1024, F=4096, E=8, top-1, cf=1.25)
#define NTOK 16384
#define DDIM 1024
#define EEXP 8
#define FDIM 4096
#define CAP  2560            // ceil(16384/8 * 1.25)
#define NBLK 1024            // routing blocks, 16 tokens each
#define TPB  16
#define LN_EPS 1e-5f

#define BM 128
#define BN 128
#define BK 32

typedef __bf16 bf16;
typedef __bf16 bf16x8 __attribute__((ext_vector_type(8)));
typedef float  f32x4  __attribute__((ext_vector_type(4)));

__device__ static inline void async_cp16(const void* g, void* l) {
  // global -> LDS direct copy, 16B per lane. LDS dest must be wave-uniform base + lane*16.
  __builtin_amdgcn_global_load_lds((const __attribute__((address_space(1))) void*)g,
                                   (__attribute__((address_space(3))) void*)l,
                                   16, 0, 0);
}

// ---------------- router: logits, softmax top-1, per-block expert counts ----------------
__global__ void router_kernel(const float* __restrict__ x, const float* __restrict__ rw,
                              int* __restrict__ top_idx, float* __restrict__ top_val,
                              int* __restrict__ block_counts, float* __restrict__ sum_probs) {
  __shared__ float s_rw[EEXP * DDIM];   // transposed [e][d] so inner reads are conflict-free
  __shared__ float s_p[EEXP];
  __shared__ int   s_c[EEXP];
  const int tid = threadIdx.x;
  for (int i = tid; i < EEXP * DDIM; i += 256) {
    int e = i >> 10, d = i & (DDIM - 1);
    s_rw[i] = rw[d * EEXP + e];
  }
  if (tid < EEXP) { s_p[tid] = 0.f; s_c[tid] = 0; }
  __syncthreads();
  const int wave = tid >> 6, lane = tid & 63;
  for (int it = 0; it < 4; ++it) {
    const int t = blockIdx.x * TPB + wave * 4 + it;
    const float* xr = x + (size_t)t * DDIM;
    float acc[EEXP];
#pragma unroll
    for (int e = 0; e < EEXP; ++e) acc[e] = 0.f;
    for (int i = 0; i < DDIM / 64; ++i) {
      const int d = i * 64 + lane;
      const float xv = xr[d];
#pragma unroll
      for (int e = 0; e < EEXP; ++e) acc[e] += xv * s_rw[e * DDIM + d];
    }
#pragma unroll
    for (int off = 32; off > 0; off >>= 1) {
#pragma unroll
      for (int e = 0; e < EEXP; ++e) acc[e] += __shfl_down(acc[e], off);
    }
    if (lane == 0) {
      float m = acc[0]; int bi = 0;
#pragma unroll
      for (int e = 1; e < EEXP; ++e) if (acc[e] > m) { m = acc[e]; bi = e; }
      float p[EEXP], s = 0.f;
#pragma unroll
      for (int e = 0; e < EEXP; ++e) { p[e] = __expf(acc[e] - m); s += p[e]; }
      const float inv = 1.f / s;        // top-1 prob = exp(0)/s
      top_idx[t] = bi;
      top_val[t] = inv;
#pragma unroll
      for (int e = 0; e < EEXP; ++e) atomicAdd(&s_p[e], p[e] * inv);
      atomicAdd(&s_c[bi], 1);
    }
  }
  __syncthreads();
  if (tid < EEXP) {
    atomicAdd(&sum_probs[tid], s_p[tid]);
    block_counts[blockIdx.x * EEXP + tid] = s_c[tid];
  }
}

// ---------------- exclusive scan of block counts (token order) ----------------
__global__ void scan_kernel(const int* __restrict__ block_counts, int* __restrict__ block_base,
                            int* __restrict__ counts) {
  __shared__ int s_sum[EEXP][32];
  __shared__ int s_base[EEXP][32];
  const int tid = threadIdx.x;
  const int e = tid >> 5, c = tid & 31;     // chunk c covers blocks [c*32, c*32+32)
  int sum = 0;
  for (int b = c * 32; b < c * 32 + 32; ++b) sum += block_counts[b * EEXP + e];
  s_sum[e][c] = sum;
  __syncthreads();
  if (c == 0) {
    int run = 0;
    for (int j = 0; j < 32; ++j) { s_base[e][j] = run; run += s_sum[e][j]; }
    counts[e] = run;                        // pre-capacity totals, used by lb_loss
  }
  __syncthreads();
  int run = s_base[e][c];
  for (int b = c * 32; b < c * 32 + 32; ++b) {
    block_base[b * EEXP + e] = run;
    run += block_counts[b * EEXP + e];
  }
}

// ---------------- dispatch: token-order ranks, scatter x -> bf16 expert buffers ----------------
__global__ void dispatch_kernel(const float* __restrict__ x, const int* __restrict__ top_idx,
                                const int* __restrict__ block_base, int* __restrict__ pos_out,
                                int* __restrict__ slot_token, bf16* __restrict__ buf) {
  __shared__ int s_e[TPB];
  __shared__ int s_slot[TPB];
  const int tid = threadIdx.x;
  const int blk = blockIdx.x;
  if (tid < TPB) s_e[tid] = top_idx[blk * TPB + tid];
  __syncthreads();
  if (tid < TPB) {
    const int e = s_e[tid];
    int rank = 0;
    for (int j = 0; j < tid; ++j) rank += (s_e[j] == e);
    const int p = block_base[blk * EEXP + e] + rank;
    const int t = blk * TPB + tid;
    pos_out[t] = p;
    int slot = -1;
    if (p < CAP) { slot = e * CAP + p; slot_token[slot] = t; }
    s_slot[tid] = slot;
  }
  __syncthreads();
  const int wave = tid >> 6, lane = tid & 63;
  for (int i = wave * 4; i < wave * 4 + 4; ++i) {
    const int slot = s_slot[i];
    if (slot < 0) continue;
    const int t = blk * TPB + i;
    const float4* src = (const float4*)(x + (size_t)t * DDIM);
    bf16* dst = buf + (size_t)slot * DDIM;
#pragma unroll
    for (int c = 0; c < 4; ++c) {
      float4 v = src[c * 64 + lane];
      union { bf16 h[4]; uint2 u; } pk;
      pk.h[0] = (bf16)v.x; pk.h[1] = (bf16)v.y; pk.h[2] = (bf16)v.z; pk.h[3] = (bf16)v.w;
      ((uint2*)dst)[c * 64 + lane] = pk.u;
    }
  }
}

// ---------------- fp32 [K][N] -> bf16 [N][K] cast+transpose (per expert) ----------------
__global__ void transpose_cast_kernel(const float* __restrict__ in, bf16* __restrict__ out,
                                      int K, int Nn) {
  __shared__ float tile[32][33];
  const int tx = threadIdx.x & 31, ty = threadIdx.x >> 5;   // ty in 0..7
  const int e = blockIdx.z;
  const int nb = blockIdx.x * 32, kb = blockIdx.y * 32;
  const float* src = in + (size_t)e * K * Nn;
  bf16* dst = out + (size_t)e * K * Nn;
#pragma unroll
  for (int r = 0; r < 4; ++r) {
    const int k = ty + r * 8;
    tile[k][tx] = src[(size_t)(kb + k) * Nn + nb + tx];
  }
  __syncthreads();
#pragma unroll
  for (int r = 0; r < 4; ++r) {
    const int n = ty + r * 8;
    dst[(size_t)(nb + n) * K + kb + tx] = (bf16)tile[tx][n];
  }
}

// ---------------- fused gate+up GEMM + SwiGLU: H = silu(A Wg) * (A Wu)  (bf16) ----------------
// A: [CAP][DDIM] bf16 (per expert), Wg/Wu: [FDIM][DDIM] bf16 ([n][k]), H: [CAP][FDIM] bf16
__global__ void gemm_gu_kernel(const bf16* __restrict__ Abuf, const bf16* __restrict__ Wg,
                               const bf16* __restrict__ Wu, bf16* __restrict__ Hout) {
  __shared__ bf16 sA[BM * BK];
  __shared__ bf16 sG[BN * BK];
  __shared__ bf16 sU[BN * BK];
  const int tid = threadIdx.x;
  const int wave = tid >> 6, lane = tid & 63;
  const int e = blockIdx.z;
  const int m0 = blockIdx.x * BM;
  const int n0 = blockIdx.y * BN;
  const bf16* A = Abuf + (size_t)e * CAP * DDIM + (size_t)m0 * DDIM;
  const bf16* G = Wg + (size_t)e * FDIM * DDIM + (size_t)n0 * DDIM;
  const bf16* U = Wu + (size_t)e * FDIM * DDIM + (size_t)n0 * DDIM;

  const f32x4 zero4 = {0.f, 0.f, 0.f, 0.f};
  f32x4 accG[4][4], accU[4][4];
#pragma unroll
  for (int i = 0; i < 4; ++i)
#pragma unroll
    for (int j = 0; j < 4; ++j) { accG[i][j] = zero4; accU[i][j] = zero4; }

  const int quad = lane >> 4, lr = lane & 15;
  const int wm = (wave & 1) * 64, wn = (wave >> 1) * 64;

  const int off0 = tid * 16;            // byte offset of this thread's first 16B piece
  const int off1 = off0 + 4096;
  const int r0 = off0 >> 6, c0 = (off0 & 63) >> 1;   // tile row / col(elem), row stride 32 elem
  const int r1 = off1 >> 6, c1 = (off1 & 63) >> 1;

  for (int kb = 0; kb < DDIM; kb += BK) {
    __syncthreads();
    async_cp16(A + (size_t)r0 * DDIM + kb + c0, (char*)sA + off0);
    async_cp16(A + (size_t)r1 * DDIM + kb + c1, (char*)sA + off1);
    async_cp16(G + (size_t)r0 * DDIM + kb + c0, (char*)sG + off0);
    async_cp16(G + (size_t)r1 * DDIM + kb + c1, (char*)sG + off1);
    async_cp16(U + (size_t)r0 * DDIM + kb + c0, (char*)sU + off0);
    async_cp16(U + (size_t)r1 * DDIM + kb + c1, (char*)sU + off1);
    __syncthreads();
    bf16x8 af[4], gf[4], uf[4];
#pragma unroll
    for (int i = 0; i < 4; ++i) {
      af[i] = *(const bf16x8*)(sA + (wm + i * 16 + lr) * BK + quad * 8);
      gf[i] = *(const bf16x8*)(sG + (wn + i * 16 + lr) * BK + quad * 8);
      uf[i] = *(const bf16x8*)(sU + (wn + i * 16 + lr) * BK + quad * 8);
    }
#pragma unroll
    for (int mi = 0; mi < 4; ++mi)
#pragma unroll
      for (int ni = 0; ni < 4; ++ni) {
        accG[mi][ni] = __builtin_amdgcn_mfma_f32_16x16x32_bf16(af[mi], gf[ni], accG[mi][ni], 0, 0, 0);
        accU[mi][ni] = __builtin_amdgcn_mfma_f32_16x16x32_bf16(af[mi], uf[ni], accU[mi][ni], 0, 0, 0);
      }
  }
  bf16* Hrow = Hout + (size_t)e * CAP * FDIM;
#pragma unroll
  for (int mi = 0; mi < 4; ++mi)
#pragma unroll
    for (int ni = 0; ni < 4; ++ni)
#pragma unroll
      for (int r = 0; r < 4; ++r) {
        const int row = m0 + wm + mi * 16 + quad * 4 + r;   // C/D: row = quad*4+reg
        const int col = n0 + wn + ni * 16 + lr;             //      col = lane&15
        const float g = accG[mi][ni][r];
        const float u = accU[mi][ni][r];
        const float h = (g / (1.f + __expf(-g))) * u;       // silu(g) * u
        Hrow[(size_t)row * FDIM + col] = (bf16)h;
      }
}

// ---------------- down GEMM + scatter-combine: res[t] = y[slot] * top_val[t] ----------------
// A: H [CAP][FDIM] bf16, B: Wd [DDIM][FDIM] bf16 ([n][k])
__global__ void gemm_down_kernel(const bf16* __restrict__ Hbuf, const bf16* __restrict__ Wd,
                                 const int* __restrict__ slot_token, const float* __restrict__ top_val,
                                 float* __restrict__ res) {
  __shared__ bf16 sA[BM * BK];
  __shared__ bf16 sB[BN * BK];
  const int tid = threadIdx.x;
  const int wave = tid >> 6, lane = tid & 63;
  const int e = blockIdx.z;
  const int m0 = blockIdx.x * BM;
  const int n0 = blockIdx.y * BN;
  const bf16* A = Hbuf + (size_t)e * CAP * FDIM + (size_t)m0 * FDIM;
  const bf16* B = Wd + (size_t)e * DDIM * FDIM + (size_t)n0 * FDIM;

  const f32x4 zero4 = {0.f, 0.f, 0.f, 0.f};
  f32x4 acc[4][4];
#pragma unroll
  for (int i = 0; i < 4; ++i)
#pragma unroll
    for (int j = 0; j < 4; ++j) acc[i][j] = zero4;

  const int quad = lane >> 4, lr = lane & 15;
  const int wm = (wave & 1) * 64, wn = (wave >> 1) * 64;

  const int off0 = tid * 16;
  const int off1 = off0 + 4096;
  const int r0 = off0 >> 6, c0 = (off0 & 63) >> 1;
  const int r1 = off1 >> 6, c1 = (off1 & 63) >> 1;

  for (int kb = 0; kb < FDIM; kb += BK) {
    __syncthreads();
    async_cp16(A + (size_t)r0 * FDIM + kb + c0, (char*)sA + off0);
    async_cp16(A + (size_t)r1 * FDIM + kb + c1, (char*)sA + off1);
    async_cp16(B + (size_t)r0 * FDIM + kb + c0, (char*)sB + off0);
    async_cp16(B + (size_t)r1 * FDIM + kb + c1, (char*)sB + off1);
    __syncthreads();
    bf16x8 af[4], bfg[4];
#pragma unroll
    for (int i = 0; i < 4; ++i) {
      af[i]  = *(const bf16x8*)(sA + (wm + i * 16 + lr) * BK + quad * 8);
      bfg[i] = *(const bf16x8*)(sB + (wn + i * 16 + lr) * BK + quad * 8);
    }
#pragma unroll
    for (int mi = 0; mi < 4; ++mi)
#pragma unroll
      for (int ni = 0; ni < 4; ++ni)
        acc[mi][ni] = __builtin_amdgcn_mfma_f32_16x16x32_bf16(af[mi], bfg[ni], acc[mi][ni], 0, 0, 0);
  }
#pragma unroll
  for (int mi = 0; mi < 4; ++mi)
#pragma unroll
    for (int r = 0; r < 4; ++r) {
      const int slotrow = m0 + wm + mi * 16 + quad * 4 + r;
      const int t = slot_token[e * CAP + slotrow];
      if (t < 0) continue;                       // empty or dropped slot
      const float v = top_val[t];
      float* dst = res + (size_t)t * DDIM + n0 + wn;
#pragma unroll
      for (int ni = 0; ni < 4; ++ni)
        dst[ni * 16 + lr] = acc[mi][ni][r] * v;
    }
}

// ---------------- residual + LayerNorm (one wave per token) ----------------
__global__ void ln_kernel(const float* __restrict__ x, const float* __restrict__ res,
                          const int* __restrict__ pos, const float* __restrict__ gamma,
                          const float* __restrict__ beta, float* __restrict__ out) {
  const int wave = threadIdx.x >> 6, lane = threadIdx.x & 63;
  const int t = blockIdx.x * 4 + wave;
  const bool keep = pos[t] < CAP;
  const float4* xr = (const float4*)(x + (size_t)t * DDIM);
  const float4* rr = (const float4*)(res + (size_t)t * DDIM);
  float4 v[4];
#pragma unroll
  for (int c = 0; c < 4; ++c) {
    float4 a = xr[c * 64 + lane];
    if (keep) {
      float4 b = rr[c * 64 + lane];
      a.x += b.x; a.y += b.y; a.z += b.z; a.w += b.w;
    }
    v[c] = a;
  }
  float s = 0.f, ss = 0.f;
#pragma unroll
  for (int c = 0; c < 4; ++c) {
    s  += v[c].x + v[c].y + v[c].z + v[c].w;
    ss += v[c].x * v[c].x + v[c].y * v[c].y + v[c].z * v[c].z + v[c].w * v[c].w;
  }
#pragma unroll
  for (int off = 32; off > 0; off >>= 1) {
    s  += __shfl_down(s, off);
    ss += __shfl_down(ss, off);
  }
  s  = __shfl(s, 0);
  ss = __shfl(ss, 0);
  const float mu = s * (1.f / DDIM);
  const float var = ss * (1.f / DDIM) - mu * mu;
  const float rstd = rsqrtf(var + LN_EPS);
  float4* outr = (float4*)(out + (size_t)t * DDIM);
#pragma unroll
  for (int c = 0; c < 4; ++c) {
    const float4 g4 = ((const float4*)gamma)[c * 64 + lane];
    const float4 b4 = ((const float4*)beta)[c * 64 + lane];
    float4 o;
    o.x = (v[c].x - mu) * rstd * g4.x + b4.x;
    o.y = (v[c].y - mu) * rstd * g4.y + b4.y;
    o.z = (v[c].z - mu) * rstd * g4.z + b4.z;
    o.w = (v[c].w - mu) * rstd * g4.w + b4.w;
    outr[c * 64 + lane] = o;
  }
}

// ---------------- load-balance loss scalar ----------------
__global__ void lb_kernel(const int* __restrict__ counts, const float* __restrict__ sum_probs,
                          float* __restrict__ out_lb) {
  if (threadIdx.x == 0) {
    float lb = 0.f;
    for (int e = 0; e < EEXP; ++e)
      lb += ((float)counts[e] / (float)NTOK) * (sum_probs[e] / (float)NTOK);
    out_lb[0] = (float)EEXP * lb;
  }
}

extern "C" void kernel_launch(void* const* d_in, const int* in_sizes, int n_in,
                              void* d_out, int out_size, void* d_ws, size_t ws_size,
                              hipStream_t stream) {
  (void)in_sizes; (void)n_in; (void)out_size; (void)ws_size;
  const float* x      = (const float*)d_in[0];
  const float* rw     = (const float*)d_in[1];
  const float* gate_w = (const float*)d_in[2];
  const float* up_w   = (const float*)d_in[3];
  const float* down_w = (const float*)d_in[4];
  const float* ln_g   = (const float*)d_in[5];
  const float* ln_b   = (const float*)d_in[6];
  float* out = (float*)d_out;

  char* ws = (char*)d_ws;
  size_t off = 0;
  auto alloc = [&](size_t bytes) -> char* {
    char* p = ws + off;
    off += (bytes + 255) & ~(size_t)255;
    return p;
  };
  bf16*  wg_t = (bf16*)alloc((size_t)EEXP * FDIM * DDIM * 2);   //  64 MiB
  bf16*  wu_t = (bf16*)alloc((size_t)EEXP * FDIM * DDIM * 2);   //  64 MiB
  bf16*  wd_t = (bf16*)alloc((size_t)EEXP * DDIM * FDIM * 2);   //  64 MiB
  bf16*  Hbuf = (bf16*)alloc((size_t)EEXP * CAP * FDIM * 2);    // 160 MiB
  bf16*  Abuf = (bf16*)alloc((size_t)EEXP * CAP * DDIM * 2);    //  40 MiB
  float* res  = (float*)alloc((size_t)NTOK * DDIM * 4);         //  64 MiB
  int*   top_idx      = (int*)alloc((size_t)NTOK * 4);
  float* top_val      = (float*)alloc((size_t)NTOK * 4);
  int*   pos          = (int*)alloc((size_t)NTOK * 4);
  int*   slot_token   = (int*)alloc((size_t)EEXP * CAP * 4);
  int*   block_counts = (int*)alloc((size_t)NBLK * EEXP * 4);
  int*   block_base   = (int*)alloc((size_t)NBLK * EEXP * 4);
  int*   counts       = (int*)alloc((size_t)EEXP * 4);
  float* sum_probs    = (float*)alloc((size_t)EEXP * 4);

  // ws is re-poisoned 0xAA before every timed call — re-init what we accumulate into / gather from
  hipMemsetAsync(Abuf, 0, (size_t)EEXP * CAP * DDIM * 2, stream);   // zero rows for unfilled slots
  hipMemsetAsync(slot_token, 0xFF, (size_t)EEXP * CAP * 4, stream); // -1 sentinel
  hipMemsetAsync(sum_probs, 0, (size_t)EEXP * 4, stream);

  transpose_cast_kernel<<<dim3(FDIM / 32, DDIM / 32, EEXP), 256, 0, stream>>>(gate_w, wg_t, DDIM, FDIM);
  transpose_cast_kernel<<<dim3(FDIM / 32, DDIM / 32, EEXP), 256, 0, stream>>>(up_w,   wu_t, DDIM, FDIM);
  transpose_cast_kernel<<<dim3(DDIM / 32, FDIM / 32, EEXP), 256, 0, stream>>>(down_w, wd_t, FDIM, DDIM);
  router_kernel<<<NBLK, 256, 0, stream>>>(x, rw, top_idx, top_val, block_counts, sum_probs);
  scan_kernel<<<1, 256, 0, stream>>>(block_counts, block_base, counts);
  dispatch_kernel<<<NBLK, 256, 0, stream>>>(x, top_idx, block_base, pos, slot_token, Abuf);
  gemm_gu_kernel<<<dim3(CAP / BM, FDIM / BN, EEXP), 256, 0, stream>>>(Abuf, wg_t, wu_t, Hbuf);
  gemm_down_kernel<<<dim3(CAP / BM, DDIM / BN, EEXP), 256, 0, stream>>>(Hbuf, wd_t, slot_token, top_val, res);
  ln_kernel<<<NTOK / 4, 256, 0, stream>>>(x, res, pos, ln_g, ln_b, out);
  lb_kernel<<<1, 64, 0, stream>>>(counts, sum_probs, out + (size_t)NTOK * DDIM);
}

// Round 2
// 1251.749 us; speedup vs baseline: 3.6810x; 3.6810x over previous
//
#include <hip/hip_runtime.h>
#include <hip/hip_bf16.h>
#include <math.h>
#include <stdint.h>

// Problem constants (B=4, T=4096, D=1024, F=4096, E=8, top-1, cf=1.25)
#define NTOK 16384
#define DDIM 1024
#define EEXP 8
#define FDIM 4096
#define CAP  2560            // ceil(16384/8 * 1.25)
#define NBLK 1024            // routing blocks, 16 tokens each
#define TPB  16
#define LN_EPS 1e-5f

#define BM 128
#define BN 128
#define BK 32

typedef __bf16 bf16;
typedef __bf16 bf16x8 __attribute__((ext_vector_type(8)));
typedef float  f32x4  __attribute__((ext_vector_type(4)));

__device__ static inline void async_cp16(const void* g, void* l) {
  // global -> LDS direct copy, 16B per lane. LDS dest must be wave-uniform base + lane*16.
  __builtin_amdgcn_global_load_lds((const __attribute__((address_space(1))) void*)g,
                                   (__attribute__((address_space(3))) void*)l,
                                   16, 0, 0);
}

// ---------------- router: logits, softmax top-1, per-block expert counts ----------------
__global__ void router_kernel(const float* __restrict__ x, const float* __restrict__ rw,
                              int* __restrict__ top_idx, float* __restrict__ top_val,
                              int* __restrict__ block_counts, float* __restrict__ sum_probs) {
  __shared__ float s_rw[EEXP * DDIM];   // transposed [e][d] so inner reads are conflict-free
  __shared__ float s_p[EEXP];
  __shared__ int   s_c[EEXP];
  const int tid = threadIdx.x;
  for (int i = tid; i < EEXP * DDIM; i += 256) {
    int e = i >> 10, d = i & (DDIM - 1);
    s_rw[i] = rw[d * EEXP + e];
  }
  if (tid < EEXP) { s_p[tid] = 0.f; s_c[tid] = 0; }
  __syncthreads();
  const int wave = tid >> 6, lane = tid & 63;
  for (int it = 0; it < 4; ++it) {
    const int t = blockIdx.x * TPB + wave * 4 + it;
    const float* xr = x + (size_t)t * DDIM;
    float acc[EEXP];
#pragma unroll
    for (int e = 0; e < EEXP; ++e) acc[e] = 0.f;
    for (int i = 0; i < DDIM / 64; ++i) {
      const int d = i * 64 + lane;
      const float xv = xr[d];
#pragma unroll
      for (int e = 0; e < EEXP; ++e) acc[e] += xv * s_rw[e * DDIM + d];
    }
#pragma unroll
    for (int off = 32; off > 0; off >>= 1) {
#pragma unroll
      for (int e = 0; e < EEXP; ++e) acc[e] += __shfl_down(acc[e], off);
    }
    if (lane == 0) {
      float m = acc[0]; int bi = 0;
#pragma unroll
      for (int e = 1; e < EEXP; ++e) if (acc[e] > m) { m = acc[e]; bi = e; }
      float p[EEXP], s = 0.f;
#pragma unroll
      for (int e = 0; e < EEXP; ++e) { p[e] = __expf(acc[e] - m); s += p[e]; }
      const float inv = 1.f / s;        // top-1 prob = exp(0)/s
      top_idx[t] = bi;
      top_val[t] = inv;
#pragma unroll
      for (int e = 0; e < EEXP; ++e) atomicAdd(&s_p[e], p[e] * inv);
      atomicAdd(&s_c[bi], 1);
    }
  }
  __syncthreads();
  if (tid < EEXP) {
    atomicAdd(&sum_probs[tid], s_p[tid]);
    block_counts[blockIdx.x * EEXP + tid] = s_c[tid];
  }
}

// ---------------- exclusive scan of block counts (token order) ----------------
__global__ void scan_kernel(const int* __restrict__ block_counts, int* __restrict__ block_base,
                            int* __restrict__ counts) {
  __shared__ int s_sum[EEXP][32];
  __shared__ int s_base[EEXP][32];
  const int tid = threadIdx.x;
  const int e = tid >> 5, c = tid & 31;     // chunk c covers blocks [c*32, c*32+32)
  int sum = 0;
  for (int b = c * 32; b < c * 32 + 32; ++b) sum += block_counts[b * EEXP + e];
  s_sum[e][c] = sum;
  __syncthreads();
  if (c == 0) {
    int run = 0;
    for (int j = 0; j < 32; ++j) { s_base[e][j] = run; run += s_sum[e][j]; }
    counts[e] = run;                        // pre-capacity totals, used by lb_loss
  }
  __syncthreads();
  int run = s_base[e][c];
  for (int b = c * 32; b < c * 32 + 32; ++b) {
    block_base[b * EEXP + e] = run;
    run += block_counts[b * EEXP + e];
  }
}

// ---------------- dispatch: token-order ranks, scatter x -> bf16 expert buffers ----------------
__global__ void dispatch_kernel(const float* __restrict__ x, const int* __restrict__ top_idx,
                                const int* __restrict__ block_base, int* __restrict__ pos_out,
                                int* __restrict__ slot_token, bf16* __restrict__ buf) {
  __shared__ int s_e[TPB];
  __shared__ int s_slot[TPB];
  const int tid = threadIdx.x;
  const int blk = blockIdx.x;
  if (tid < TPB) s_e[tid] = top_idx[blk * TPB + tid];
  __syncthreads();
  if (tid < TPB) {
    const int e = s_e[tid];
    int rank = 0;
    for (int j = 0; j < tid; ++j) rank += (s_e[j] == e);
    const int p = block_base[blk * EEXP + e] + rank;
    const int t = blk * TPB + tid;
    pos_out[t] = p;
    int slot = -1;
    if (p < CAP) { slot = e * CAP + p; slot_token[slot] = t; }
    s_slot[tid] = slot;
  }
  __syncthreads();
  const int wave = tid >> 6, lane = tid & 63;
  for (int i = wave * 4; i < wave * 4 + 4; ++i) {
    const int slot = s_slot[i];
    if (slot < 0) continue;
    const int t = blk * TPB + i;
    const float4* src = (const float4*)(x + (size_t)t * DDIM);
    bf16* dst = buf + (size_t)slot * DDIM;
#pragma unroll
    for (int c = 0; c < 4; ++c) {
      float4 v = src[c * 64 + lane];
      union { bf16 h[4]; uint2 u; } pk;
      pk.h[0] = (bf16)v.x; pk.h[1] = (bf16)v.y; pk.h[2] = (bf16)v.z; pk.h[3] = (bf16)v.w;
      ((uint2*)dst)[c * 64 + lane] = pk.u;
    }
  }
}

// ---------------- fp32 [K][N] -> bf16 [N][K] cast+transpose (per expert) ----------------
__global__ void transpose_cast_kernel(const float* __restrict__ in, bf16* __restrict__ out,
                                      int K, int Nn) {
  __shared__ float tile[32][33];
  const int tx = threadIdx.x & 31, ty = threadIdx.x >> 5;   // ty in 0..7
  const int e = blockIdx.z;
  const int nb = blockIdx.x * 32, kb = blockIdx.y * 32;
  const float* src = in + (size_t)e * K * Nn;
  bf16* dst = out + (size_t)e * K * Nn;
#pragma unroll
  for (int r = 0; r < 4; ++r) {
    const int k = ty + r * 8;
    tile[k][tx] = src[(size_t)(kb + k) * Nn + nb + tx];
  }
  __syncthreads();
#pragma unroll
  for (int r = 0; r < 4; ++r) {
    const int n = ty + r * 8;
    dst[(size_t)(nb + n) * K + kb + tx] = (bf16)tile[tx][n];
  }
}

// ---------------- fused gate+up GEMM + SwiGLU: H = silu(A Wg) * (A Wu)  (bf16) ----------------
// A: [CAP][DDIM] bf16 (per expert), Wg/Wu: [FDIM][DDIM] bf16 ([n][k]), H: [CAP][FDIM] bf16
// __launch_bounds__(256,2): 2 waves/EU min -> VGPR cap 256. Without it the compiler
// compiled for the default occupancy contract, capped at 64 VGPRs, and spilled both
// accumulator arrays to scratch (R1: WRITE_SIZE 11.7 GB vs 167 MB ideal, MfmaUtil 3.9%).
__global__ __launch_bounds__(256, 2)
void gemm_gu_kernel(const bf16* __restrict__ Abuf, const bf16* __restrict__ Wg,
                    const bf16* __restrict__ Wu, bf16* __restrict__ Hout) {
  __shared__ bf16 sA[BM * BK];
  __shared__ bf16 sG[BN * BK];
  __shared__ bf16 sU[BN * BK];
  const int tid = threadIdx.x;
  const int wave = tid >> 6, lane = tid & 63;
  const int e = blockIdx.z;
  const int m0 = blockIdx.x * BM;
  const int n0 = blockIdx.y * BN;
  const bf16* A = Abuf + (size_t)e * CAP * DDIM + (size_t)m0 * DDIM;
  const bf16* G = Wg + (size_t)e * FDIM * DDIM + (size_t)n0 * DDIM;
  const bf16* U = Wu + (size_t)e * FDIM * DDIM + (size_t)n0 * DDIM;

  const f32x4 zero4 = {0.f, 0.f, 0.f, 0.f};
  f32x4 accG[4][4], accU[4][4];
#pragma unroll
  for (int i = 0; i < 4; ++i)
#pragma unroll
    for (int j = 0; j < 4; ++j) { accG[i][j] = zero4; accU[i][j] = zero4; }

  const int quad = lane >> 4, lr = lane & 15;
  const int wm = (wave & 1) * 64, wn = (wave >> 1) * 64;

  const int off0 = tid * 16;            // byte offset of this thread's first 16B piece
  const int off1 = off0 + 4096;
  const int r0 = off0 >> 6, c0 = (off0 & 63) >> 1;   // tile row / col(elem), row stride 32 elem
  const int r1 = off1 >> 6, c1 = (off1 & 63) >> 1;

  for (int kb = 0; kb < DDIM; kb += BK) {
    __syncthreads();
    async_cp16(A + (size_t)r0 * DDIM + kb + c0, (char*)sA + off0);
    async_cp16(A + (size_t)r1 * DDIM + kb + c1, (char*)sA + off1);
    async_cp16(G + (size_t)r0 * DDIM + kb + c0, (char*)sG + off0);
    async_cp16(G + (size_t)r1 * DDIM + kb + c1, (char*)sG + off1);
    async_cp16(U + (size_t)r0 * DDIM + kb + c0, (char*)sU + off0);
    async_cp16(U + (size_t)r1 * DDIM + kb + c1, (char*)sU + off1);
    __syncthreads();
    bf16x8 af[4], gf[4], uf[4];
#pragma unroll
    for (int i = 0; i < 4; ++i) {
      af[i] = *(const bf16x8*)(sA + (wm + i * 16 + lr) * BK + quad * 8);
      gf[i] = *(const bf16x8*)(sG + (wn + i * 16 + lr) * BK + quad * 8);
      uf[i] = *(const bf16x8*)(sU + (wn + i * 16 + lr) * BK + quad * 8);
    }
#pragma unroll
    for (int mi = 0; mi < 4; ++mi)
#pragma unroll
      for (int ni = 0; ni < 4; ++ni) {
        accG[mi][ni] = __builtin_amdgcn_mfma_f32_16x16x32_bf16(af[mi], gf[ni], accG[mi][ni], 0, 0, 0);
        accU[mi][ni] = __builtin_amdgcn_mfma_f32_16x16x32_bf16(af[mi], uf[ni], accU[mi][ni], 0, 0, 0);
      }
  }
  bf16* Hrow = Hout + (size_t)e * CAP * FDIM;
#pragma unroll
  for (int mi = 0; mi < 4; ++mi)
#pragma unroll
    for (int ni = 0; ni < 4; ++ni)
#pragma unroll
      for (int r = 0; r < 4; ++r) {
        const int row = m0 + wm + mi * 16 + quad * 4 + r;   // C/D: row = quad*4+reg
        const int col = n0 + wn + ni * 16 + lr;             //      col = lane&15
        const float g = accG[mi][ni][r];
        const float u = accU[mi][ni][r];
        const float h = (g / (1.f + __expf(-g))) * u;       // silu(g) * u
        Hrow[(size_t)row * FDIM + col] = (bf16)h;
      }
}

// ---------------- down GEMM + scatter-combine: res[t] = y[slot] * top_val[t] ----------------
// A: H [CAP][FDIM] bf16, B: Wd [DDIM][FDIM] bf16 ([n][k])
__global__ __launch_bounds__(256, 2)
void gemm_down_kernel(const bf16* __restrict__ Hbuf, const bf16* __restrict__ Wd,
                      const int* __restrict__ slot_token, const float* __restrict__ top_val,
                      float* __restrict__ res) {
  __shared__ bf16 sA[BM * BK];
  __shared__ bf16 sB[BN * BK];
  const int tid = threadIdx.x;
  const int wave = tid >> 6, lane = tid & 63;
  const int e = blockIdx.z;
  const int m0 = blockIdx.x * BM;
  const int n0 = blockIdx.y * BN;
  const bf16* A = Hbuf + (size_t)e * CAP * FDIM + (size_t)m0 * FDIM;
  const bf16* B = Wd + (size_t)e * DDIM * FDIM + (size_t)n0 * FDIM;

  const f32x4 zero4 = {0.f, 0.f, 0.f, 0.f};
  f32x4 acc[4][4];
#pragma unroll
  for (int i = 0; i < 4; ++i)
#pragma unroll
    for (int j = 0; j < 4; ++j) acc[i][j] = zero4;

  const int quad = lane >> 4, lr = lane & 15;
  const int wm = (wave & 1) * 64, wn = (wave >> 1) * 64;

  const int off0 = tid * 16;
  const int off1 = off0 + 4096;
  const int r0 = off0 >> 6, c0 = (off0 & 63) >> 1;
  const int r1 = off1 >> 6, c1 = (off1 & 63) >> 1;

  for (int kb = 0; kb < FDIM; kb += BK) {
    __syncthreads();
    async_cp16(A + (size_t)r0 * FDIM + kb + c0, (char*)sA + off0);
    async_cp16(A + (size_t)r1 * FDIM + kb + c1, (char*)sA + off1);
    async_cp16(B + (size_t)r0 * FDIM + kb + c0, (char*)sB + off0);
    async_cp16(B + (size_t)r1 * FDIM + kb + c1, (char*)sB + off1);
    __syncthreads();
    bf16x8 af[4], bfg[4];
#pragma unroll
    for (int i = 0; i < 4; ++i) {
      af[i]  = *(const bf16x8*)(sA + (wm + i * 16 + lr) * BK + quad * 8);
      bfg[i] = *(const bf16x8*)(sB + (wn + i * 16 + lr) * BK + quad * 8);
    }
#pragma unroll
    for (int mi = 0; mi < 4; ++mi)
#pragma unroll
      for (int ni = 0; ni < 4; ++ni)
        acc[mi][ni] = __builtin_amdgcn_mfma_f32_16x16x32_bf16(af[mi], bfg[ni], acc[mi][ni], 0, 0, 0);
  }
#pragma unroll
  for (int mi = 0; mi < 4; ++mi)
#pragma unroll
    for (int r = 0; r < 4; ++r) {
      const int slotrow = m0 + wm + mi * 16 + quad * 4 + r;
      const int t = slot_token[e * CAP + slotrow];
      if (t < 0) continue;                       // empty or dropped slot
      const float v = top_val[t];
      float* dst = res + (size_t)t * DDIM + n0 + wn;
#pragma unroll
      for (int ni = 0; ni < 4; ++ni)
        dst[ni * 16 + lr] = acc[mi][ni][r] * v;
    }
}

// ---------------- residual + LayerNorm (one wave per token) ----------------
__global__ void ln_kernel(const float* __restrict__ x, const float* __restrict__ res,
                          const int* __restrict__ pos, const float* __restrict__ gamma,
                          const float* __restrict__ beta, float* __restrict__ out) {
  const int wave = threadIdx.x >> 6, lane = threadIdx.x & 63;
  const int t = blockIdx.x * 4 + wave;
  const bool keep = pos[t] < CAP;
  const float4* xr = (const float4*)(x + (size_t)t * DDIM);
  const float4* rr = (const float4*)(res + (size_t)t * DDIM);
  float4 v[4];
#pragma unroll
  for (int c = 0; c < 4; ++c) {
    float4 a = xr[c * 64 + lane];
    if (keep) {
      float4 b = rr[c * 64 + lane];
      a.x += b.x; a.y += b.y; a.z += b.z; a.w += b.w;
    }
    v[c] = a;
  }
  float s = 0.f, ss = 0.f;
#pragma unroll
  for (int c = 0; c < 4; ++c) {
    s  += v[c].x + v[c].y + v[c].z + v[c].w;
    ss += v[c].x * v[c].x + v[c].y * v[c].y + v[c].z * v[c].z + v[c].w * v[c].w;
  }
#pragma unroll
  for (int off = 32; off > 0; off >>= 1) {
    s  += __shfl_down(s, off);
    ss += __shfl_down(ss, off);
  }
  s  = __shfl(s, 0);
  ss = __shfl(ss, 0);
  const float mu = s * (1.f / DDIM);
  const float var = ss * (1.f / DDIM) - mu * mu;
  const float rstd = rsqrtf(var + LN_EPS);
  float4* outr = (float4*)(out + (size_t)t * DDIM);
#pragma unroll
  for (int c = 0; c < 4; ++c) {
    const float4 g4 = ((const float4*)gamma)[c * 64 + lane];
    const float4 b4 = ((const float4*)beta)[c * 64 + lane];
    float4 o;
    o.x = (v[c].x - mu) * rstd * g4.x + b4.x;
    o.y = (v[c].y - mu) * rstd * g4.y + b4.y;
    o.z = (v[c].z - mu) * rstd * g4.z + b4.z;
    o.w = (v[c].w - mu) * rstd * g4.w + b4.w;
    outr[c * 64 + lane] = o;
  }
}

// ---------------- load-balance loss scalar ----------------
__global__ void lb_kernel(const int* __restrict__ counts, const float* __restrict__ sum_probs,
                          float* __restrict__ out_lb) {
  if (threadIdx.x == 0) {
    float lb = 0.f;
    for (int e = 0; e < EEXP; ++e)
      lb += ((float)counts[e] / (float)NTOK) * (sum_probs[e] / (float)NTOK);
    out_lb[0] = (float)EEXP * lb;
  }
}

extern "C" void kernel_launch(void* const* d_in, const int* in_sizes, int n_in,
                              void* d_out, int out_size, void* d_ws, size_t ws_size,
                              hipStream_t stream) {
  (void)in_sizes; (void)n_in; (void)out_size; (void)ws_size;
  const float* x      = (const float*)d_in[0];
  const float* rw     = (const float*)d_in[1];
  const float* gate_w = (const float*)d_in[2];
  const float* up_w   = (const float*)d_in[3];
  const float* down_w = (const float*)d_in[4];
  const float* ln_g   = (const float*)d_in[5];
  const float* ln_b   = (const float*)d_in[6];
  float* out = (float*)d_out;

  char* ws = (char*)d_ws;
  size_t off = 0;
  auto alloc = [&](size_t bytes) -> char* {
    char* p = ws + off;
    off += (bytes + 255) & ~(size_t)255;
    return p;
  };
  bf16*  wg_t = (bf16*)alloc((size_t)EEXP * FDIM * DDIM * 2);   //  64 MiB
  bf16*  wu_t = (bf16*)alloc((size_t)EEXP * FDIM * DDIM * 2);   //  64 MiB
  bf16*  wd_t = (bf16*)alloc((size_t)EEXP * DDIM * FDIM * 2);   //  64 MiB
  bf16*  Hbuf = (bf16*)alloc((size_t)EEXP * CAP * FDIM * 2);    // 160 MiB
  bf16*  Abuf = (bf16*)alloc((size_t)EEXP * CAP * DDIM * 2);    //  40 MiB
  float* res  = (float*)alloc((size_t)NTOK * DDIM * 4);         //  64 MiB
  int*   top_idx      = (int*)alloc((size_t)NTOK * 4);
  float* top_val      = (float*)alloc((size_t)NTOK * 4);
  int*   pos          = (int*)alloc((size_t)NTOK * 4);
  int*   slot_token   = (int*)alloc((size_t)EEXP * CAP * 4);
  int*   block_counts = (int*)alloc((size_t)NBLK * EEXP * 4);
  int*   block_base   = (int*)alloc((size_t)NBLK * EEXP * 4);
  int*   counts       = (int*)alloc((size_t)EEXP * 4);
  float* sum_probs    = (float*)alloc((size_t)EEXP * 4);

  // ws is re-poisoned 0xAA before every timed call — re-init what we accumulate into / gather from
  hipMemsetAsync(Abuf, 0, (size_t)EEXP * CAP * DDIM * 2, stream);   // zero rows for unfilled slots
  hipMemsetAsync(slot_token, 0xFF, (size_t)EEXP * CAP * 4, stream); // -1 sentinel
  hipMemsetAsync(sum_probs, 0, (size_t)EEXP * 4, stream);

  transpose_cast_kernel<<<dim3(FDIM / 32, DDIM / 32, EEXP), 256, 0, stream>>>(gate_w, wg_t, DDIM, FDIM);
  transpose_cast_kernel<<<dim3(FDIM / 32, DDIM / 32, EEXP), 256, 0, stream>>>(up_w,   wu_t, DDIM, FDIM);
  transpose_cast_kernel<<<dim3(DDIM / 32, FDIM / 32, EEXP), 256, 0, stream>>>(down_w, wd_t, FDIM, DDIM);
  router_kernel<<<NBLK, 256, 0, stream>>>(x, rw, top_idx, top_val, block_counts, sum_probs);
  scan_kernel<<<1, 256, 0, stream>>>(block_counts, block_base, counts);
  dispatch_kernel<<<NBLK, 256, 0, stream>>>(x, top_idx, block_base, pos, slot_token, Abuf);
  gemm_gu_kernel<<<dim3(CAP / BM, FDIM / BN, EEXP), 256, 0, stream>>>(Abuf, wg_t, wu_t, Hbuf);
  gemm_down_kernel<<<dim3(CAP / BM, DDIM / BN, EEXP), 256, 0, stream>>>(Hbuf, wd_t, slot_token, top_val, res);
  ln_kernel<<<NTOK / 4, 256, 0, stream>>>(x, res, pos, ln_g, ln_b, out);
  lb_kernel<<<1, 64, 0, stream>>>(counts, sum_probs, out + (size_t)NTOK * DDIM);
}